// Round 10
// baseline (3604.162 us; speedup 1.0000x reference)
//
#include <hip/hip_runtime.h>
#include <hip/hip_bf16.h>
#include <math.h>

#define HIDDEN 64
#define K_STEPS 10
#define SLICES 2
#define SLICE_N 51200              // 2*51200 = 102400 >= N
#define SLICE_W (SLICE_N / 4)      // packed-byte words per slice (12800 = 51.2KB LDS)
#define EPB 256                    // target edges per step-block
#define MAXN 96                    // max nodes resident in LDS per chunk
#define ACC_STRIDE 68              // floats per node row in LDS (16B aligned, bank-spread)

struct Wts { float v[K_STEPS + 1]; };

typedef float v2f __attribute__((ext_vector_type(2)));
typedef unsigned int u32x4 __attribute__((ext_vector_type(4)));

__device__ __forceinline__ float bits2f(unsigned int u) {
    union { unsigned int i; float f; } c; c.i = u; return c.f;
}
__device__ __forceinline__ unsigned int f2bf(float f) {
    union { float f; unsigned int u; } c; c.f = f;
    unsigned int u = c.u;
    return (u + 0x7FFF + ((u >> 16) & 1)) >> 16;  // RNE, low 16 bits valid
}
__device__ __forceinline__ void unpack_add(v2f acc[4], uint4 v) {
    v2f t;
    t.x = bits2f(v.x << 16); t.y = bits2f(v.x & 0xFFFF0000u); acc[0] += t;
    t.x = bits2f(v.y << 16); t.y = bits2f(v.y & 0xFFFF0000u); acc[1] += t;
    t.x = bits2f(v.z << 16); t.y = bits2f(v.z & 0xFFFF0000u); acc[2] += t;
    t.x = bits2f(v.w << 16); t.y = bits2f(v.w & 0xFFFF0000u); acc[3] += t;
}
__device__ __forceinline__ u32x4 ntload4(const uint4* p) {
    return __builtin_nontemporal_load((const u32x4*)p);
}

// ---------------- dtype sniffing ----------------
__global__ void detect_kernel(const int* __restrict__ srcw,
                              const unsigned short* __restrict__ featw,
                              int* __restrict__ flags) {
    __shared__ int odd_nonzero;
    __shared__ int exp_in_range;
    if (threadIdx.x == 0) { odd_nonzero = 0; exp_in_range = 0; }
    __syncthreads();
    int w = srcw[2 * threadIdx.x + 1];
    if (w != 0) atomicAdd(&odd_nonzero, 1);
    unsigned short f = featw[2 * threadIdx.x];
    int ex = (f >> 7) & 0xFF;
    if (ex >= 90 && ex <= 135) atomicAdd(&exp_in_range, 1);
    __syncthreads();
    if (threadIdx.x == 0) {
        flags[0] = (odd_nonzero == 0) ? 1 : 0;    // int64 indices
        flags[1] = (exp_in_range >= 240) ? 0 : 1; // fp32 feat
    }
}

// ---------------- LDS byte-packed degree histogram ----------------
__global__ void hist_kernel(const void* __restrict__ src, const void* __restrict__ dst,
                            const int* __restrict__ flags,
                            unsigned* __restrict__ partials, int E, int chunkE, int nchunks) {
    __shared__ unsigned bins[SLICE_W];
    int cx = blockIdx.x, sy = blockIdx.y, az = blockIdx.z;
    for (int i = threadIdx.x; i < SLICE_W; i += 256) bins[i] = 0;
    __syncthreads();
    const void* arr = az ? dst : src;
    int i64 = flags[0];
    int base = cx * chunkE;
    int lim = min(base + chunkE, E);
    int sliceBase = sy * SLICE_N;
    for (int e = base + threadIdx.x; e < lim; e += 256) {
        int v = i64 ? (int)((const long long*)arr)[e] : ((const int*)arr)[e];
        unsigned local = (unsigned)(v - sliceBase);
        if (local < SLICE_N)
            atomicAdd(&bins[local >> 2], 1u << ((local & 3) * 8));
    }
    __syncthreads();
    unsigned* out = partials + ((size_t)((az * SLICES + sy) * nchunks + cx)) * SLICE_W;
    for (int i = threadIdx.x; i < SLICE_W; i += 256) out[i] = bins[i];
}

// ---------------- merge partials -> degrees; per-chunk prefixes for dst ----------------
__global__ void reduce_kernel(const unsigned* __restrict__ partials,
                              unsigned* __restrict__ chunk_pre,
                              int* __restrict__ out_deg, int* __restrict__ in_deg,
                              int N, int nchunks) {
    int t = blockIdx.x * blockDim.x + threadIdx.x;
    if (t >= 2 * SLICES * SLICE_W) return;
    int a = t / (SLICES * SLICE_W);
    int r = t % (SLICES * SLICE_W);
    int s = r / SLICE_W;
    int lw = r % SLICE_W;
    const unsigned* p = partials + ((size_t)((a * SLICES + s) * nchunks)) * SLICE_W + lw;
    unsigned sum = 0;
    if (a == 1) {
        for (int c = 0; c < nchunks; ++c) {
            chunk_pre[((size_t)(c * SLICES + s)) * SLICE_W + lw] = sum;
            sum += p[(size_t)c * SLICE_W];
        }
    } else {
        for (int c = 0; c < nchunks; ++c) sum += p[(size_t)c * SLICE_W];
    }
    int nodeBase = s * SLICE_N + lw * 4;
    int* deg = a ? in_deg : out_deg;
    #pragma unroll
    for (int k = 0; k < 4; ++k) {
        int n = nodeBase + k;
        if (n < N) deg[n] = (int)((sum >> (k * 8)) & 0xFF);
    }
}

// ---------------- norms ----------------
__global__ void norm_kernel(const int* __restrict__ out_deg, const int* __restrict__ in_deg,
                            float* __restrict__ src_norm, float* __restrict__ dst_norm, int N) {
    int n = blockIdx.x * blockDim.x + threadIdx.x;
    if (n < N) {
        src_norm[n] = 1.0f / sqrtf(fmaxf((float)out_deg[n], 1.0f));
        dst_norm[n] = 1.0f / sqrtf(fmaxf((float)in_deg[n], 1.0f));
    }
}

// ---------------- scan A ----------------
__global__ void scanA_kernel(const int* __restrict__ deg, int* __restrict__ row_ptr,
                             int* __restrict__ block_sums, int N) {
    __shared__ int lds[256];
    int t = threadIdx.x;
    int base = blockIdx.x * 1024 + t * 4;
    int v0 = (base + 0 < N) ? deg[base + 0] : 0;
    int v1 = (base + 1 < N) ? deg[base + 1] : 0;
    int v2 = (base + 2 < N) ? deg[base + 2] : 0;
    int v3 = (base + 3 < N) ? deg[base + 3] : 0;
    int s = v0 + v1 + v2 + v3;
    lds[t] = s;
    __syncthreads();
    for (int off = 1; off < 256; off <<= 1) {
        int x = 0;
        if (t >= off) x = lds[t - off];
        __syncthreads();
        if (t >= off) lds[t] += x;
        __syncthreads();
    }
    int excl = lds[t] - s;
    if (t == 255) block_sums[blockIdx.x] = lds[255];
    if (base + 0 < N) row_ptr[base + 0] = excl;
    if (base + 1 < N) row_ptr[base + 1] = excl + v0;
    if (base + 2 < N) row_ptr[base + 2] = excl + v0 + v1;
    if (base + 3 < N) row_ptr[base + 3] = excl + v0 + v1 + v2;
}

// ---------------- scan B ----------------
__global__ void scanB_kernel(int* __restrict__ bs, int nb) {
    __shared__ int lds[1024];
    int t = threadIdx.x;
    int v = (t < nb) ? bs[t] : 0;
    lds[t] = v;
    __syncthreads();
    for (int off = 1; off < 1024; off <<= 1) {
        int x = 0;
        if (t >= off) x = lds[t - off];
        __syncthreads();
        if (t >= off) lds[t] += x;
        __syncthreads();
    }
    if (t < nb) bs[t] = lds[t] - v;
}

// ---------------- scan C ----------------
__global__ void scanC_kernel(const int* __restrict__ block_offs, int* __restrict__ row_ptr,
                             int N, int E) {
    int i = blockIdx.x * blockDim.x + threadIdx.x;
    if (i < N) row_ptr[i] += block_offs[i >> 10];
    if (i == 0) row_ptr[N] = E;
}

// ---------------- CSR fill (also emits per-edge row id) ----------------
__global__ void fill_kernel(const void* __restrict__ src, const void* __restrict__ dst,
                            const int* __restrict__ flags,
                            const int* __restrict__ row_ptr,
                            const unsigned* __restrict__ chunk_pre,
                            int* __restrict__ col, int* __restrict__ dstid,
                            int E, int chunkE) {
    __shared__ unsigned bins[SLICE_W];
    int cx = blockIdx.x, sy = blockIdx.y;
    for (int i = threadIdx.x; i < SLICE_W; i += 256) bins[i] = 0;
    __syncthreads();
    int i64 = flags[0];
    int base = cx * chunkE;
    int lim = min(base + chunkE, E);
    int sliceBase = sy * SLICE_N;
    const unsigned* pre_base = chunk_pre + ((size_t)(cx * SLICES + sy)) * SLICE_W;
    for (int e = base + threadIdx.x; e < lim; e += 256) {
        int s, d;
        if (i64) { s = (int)((const long long*)src)[e]; d = (int)((const long long*)dst)[e]; }
        else     { s = ((const int*)src)[e];            d = ((const int*)dst)[e]; }
        unsigned local = (unsigned)(d - sliceBase);
        if (local < SLICE_N) {
            int sh = (local & 3) * 8;
            unsigned old = atomicAdd(&bins[local >> 2], 1u << sh);
            int rank = (int)((old >> sh) & 0xFF);
            int pre = (int)((pre_base[local >> 2] >> sh) & 0xFF);
            int pos = row_ptr[d] + pre + rank;
            col[pos] = s;
            dstid[pos] = d;
        }
    }
}

// ---------------- partition: node-respecting edge blocks ----------------
__global__ void partition_kernel(const int* __restrict__ row_ptr, int* __restrict__ start,
                                 int nblocks, int N) {
    int b = blockIdx.x * blockDim.x + threadIdx.x;
    if (b > nblocks) return;
    if (b == nblocks) { start[b] = N; return; }
    int target = b * EPB;
    int lo = 0, hi = N;   // first n with row_ptr[n] >= target
    while (lo < hi) {
        int mid = (lo + hi) >> 1;
        if (row_ptr[mid] >= target) hi = mid; else lo = mid + 1;
    }
    start[b] = lo;
}

// ---------------- init ----------------
__global__ void init_kernel(const void* __restrict__ feat_raw,
                            const int* __restrict__ flags,
                            const float* __restrict__ src_norm,
                            uint4* __restrict__ hs8, float4* __restrict__ out_acc4,
                            float w0, int nchunks, int writeAcc) {
    int i = blockIdx.x * blockDim.x + threadIdx.x;
    if (i >= nchunks) return;
    int n = i >> 3;
    int c = i & 7;
    float sn = src_norm[n];
    float f[8];
    if (flags[1]) {
        float4 a = ((const float4*)feat_raw)[i * 2];
        float4 b = ((const float4*)feat_raw)[i * 2 + 1];
        f[0] = a.x; f[1] = a.y; f[2] = a.z; f[3] = a.w;
        f[4] = b.x; f[5] = b.y; f[6] = b.z; f[7] = b.w;
    } else {
        uint4 u = ((const uint4*)feat_raw)[i];
        f[0] = bits2f(u.x << 16); f[1] = bits2f(u.x & 0xFFFF0000u);
        f[2] = bits2f(u.y << 16); f[3] = bits2f(u.y & 0xFFFF0000u);
        f[4] = bits2f(u.z << 16); f[5] = bits2f(u.z & 0xFFFF0000u);
        f[6] = bits2f(u.w << 16); f[7] = bits2f(u.w & 0xFFFF0000u);
    }
    uint4 h;
    h.x = f2bf(f[0] * sn) | (f2bf(f[1] * sn) << 16);
    h.y = f2bf(f[2] * sn) | (f2bf(f[3] * sn) << 16);
    h.z = f2bf(f[4] * sn) | (f2bf(f[5] * sn) << 16);
    h.w = f2bf(f[6] * sn) | (f2bf(f[7] * sn) << 16);
    hs8[i] = h;
    if (writeAcc) {
        float4 o0, o1;
        o0.x = w0 * f[0]; o0.y = w0 * f[1]; o0.z = w0 * f[2]; o0.w = w0 * f[3];
        o1.x = w0 * f[4]; o1.y = w0 * f[5]; o1.z = w0 * f[6]; o1.w = w0 * f[7];
        size_t ob = (size_t)n * 16 + c * 2;
        out_acc4[ob] = o0;
        out_acc4[ob + 1] = o1;
    }
}

// ---------------- edge-parallel step: fully-packed gathers + LDS fp32 accumulation ----------------
__global__ __launch_bounds__(256) void step_edge(
        const uint4* __restrict__ hs8, const int* __restrict__ row_ptr,
        const int* __restrict__ col, const int* __restrict__ dstid,
        const int* __restrict__ start, const float* __restrict__ src_norm,
        const float* __restrict__ dst_norm, uint4* __restrict__ hs_next8, int N) {
    __shared__ float acc[MAXN * ACC_STRIDE];
    int b = blockIdx.x;
    int n0 = start[b], n1 = start[b + 1];
    if (n0 >= n1) return;   // uniform across block
    int tid = threadIdx.x;
    int wave = tid >> 6, lane = tid & 63;
    int slot = lane >> 3, fo = lane & 7;

    for (int c0 = n0; c0 < n1; c0 += MAXN) {
        int c1 = min(c0 + MAXN, n1);
        int nn = c1 - c0;
        int eb = row_ptr[c0];
        int ee = row_ptr[c1];
        for (int i = tid; i < nn * ACC_STRIDE; i += 256) acc[i] = 0.f;
        __syncthreads();

        for (int tb = eb + wave * 64; tb < ee; tb += 256) {
            int myE = tb + lane;
            bool ok = myE < ee;
            int myCol = ok ? col[myE] : 0;
            int myDst = ok ? dstid[myE] : c0;
            int cnt = min(64, ee - tb);
            for (int g = 0; g * 8 < cnt; ++g) {
                int idx = g * 8 + slot;
                bool act = idx < cnt;
                int pick = act ? idx : 0;
                int s = __shfl(myCol, pick);
                int dl = __shfl(myDst, pick) - c0;
                if (act) {
                    u32x4 v = ntload4(hs8 + (size_t)s * 8 + fo);
                    float* dp = &acc[dl * ACC_STRIDE + fo * 8];
                    atomicAdd(dp + 0, bits2f(v.x << 16));
                    atomicAdd(dp + 1, bits2f(v.x & 0xFFFF0000u));
                    atomicAdd(dp + 2, bits2f(v.y << 16));
                    atomicAdd(dp + 3, bits2f(v.y & 0xFFFF0000u));
                    atomicAdd(dp + 4, bits2f(v.z << 16));
                    atomicAdd(dp + 5, bits2f(v.z & 0xFFFF0000u));
                    atomicAdd(dp + 6, bits2f(v.w << 16));
                    atomicAdd(dp + 7, bits2f(v.w & 0xFFFF0000u));
                }
            }
        }
        __syncthreads();

        // epilogue: pack LDS fp32 -> bf16 hs_next, 8 feats per thread-chunk
        for (int t = tid; t < nn * 8; t += 256) {
            int ln = t >> 3, c8 = t & 7;
            int n = c0 + ln;
            float m = dst_norm[n] * src_norm[n];
            const float* ap = &acc[ln * ACC_STRIDE + c8 * 8];
            uint4 hn;
            hn.x = f2bf(ap[0] * m) | (f2bf(ap[1] * m) << 16);
            hn.y = f2bf(ap[2] * m) | (f2bf(ap[3] * m) << 16);
            hn.z = f2bf(ap[4] * m) | (f2bf(ap[5] * m) << 16);
            hn.w = f2bf(ap[6] * m) | (f2bf(ap[7] * m) << 16);
            hs_next8[(size_t)n * 8 + c8] = hn;
        }
        __syncthreads();
    }
}

// ---------------- acc-mode fallback (node-based gather, unchanged) ----------------
__device__ __forceinline__ void gather_range(const uint4* __restrict__ hs8,
                                             const int* __restrict__ col,
                                             int beg, int end, int lane,
                                             v2f a0[4]) {
    int grp = lane >> 3;
    int fo = lane & 7;
    for (int ebase = beg; ebase < end; ebase += 64) {
        int myE = ebase + lane;
        int myCol = (myE < end) ? col[myE] : 0;
        int cnt = min(64, end - ebase);
        int j = 0;
        while (j < cnt) {
            int g = j + grp;
            bool act = g < cnt;
            int s = __shfl(myCol, act ? g : 0);
            uint4 v = hs8[(size_t)s * 8 + fo];
            if (act) unpack_add(a0, v);
            j += 8;
        }
    }
}
__device__ __forceinline__ void reduce_slots(v2f a[4], int lane) {
    #pragma unroll
    for (int off = 8; off <= 32; off <<= 1) {
        #pragma unroll
        for (int k = 0; k < 4; ++k) {
            v2f t;
            t.x = __shfl_xor(a[k].x, off);
            t.y = __shfl_xor(a[k].y, off);
            a[k] += t;
        }
    }
}
template <bool LAST>
__global__ __launch_bounds__(256) void step_acc(
        const uint4* __restrict__ hs8, const int* __restrict__ row_ptr,
        const int* __restrict__ col, const float* __restrict__ src_norm,
        const float* __restrict__ dst_norm, uint4* __restrict__ hs_next8,
        float4* __restrict__ out_acc4, float4* __restrict__ out4, float w, int N) {
    int wid = (blockIdx.x * 256 + threadIdx.x) >> 6;
    int nw = (gridDim.x * 256) >> 6;
    int lane = threadIdx.x & 63;
    for (int node = wid; node < N; node += nw) {
        v2f a[4] = {v2f{0.f,0.f}, v2f{0.f,0.f}, v2f{0.f,0.f}, v2f{0.f,0.f}};
        gather_range(hs8, col, row_ptr[node], row_ptr[node + 1], lane, a);
        reduce_slots(a, lane);
        if (lane < 8) {
            float dn = dst_norm[node];
            float h0 = a[0].x * dn, h1 = a[0].y * dn, h2 = a[1].x * dn, h3 = a[1].y * dn;
            float h4 = a[2].x * dn, h5 = a[2].y * dn, h6 = a[3].x * dn, h7 = a[3].y * dn;
            size_t ob = (size_t)node * 16 + lane * 2;
            float4 o0 = out_acc4[ob];
            float4 o1 = out_acc4[ob + 1];
            o0.x += w * h0; o0.y += w * h1; o0.z += w * h2; o0.w += w * h3;
            o1.x += w * h4; o1.y += w * h5; o1.z += w * h6; o1.w += w * h7;
            if (LAST) {
                out4[ob] = o0;
                out4[ob + 1] = o1;
            } else {
                out_acc4[ob] = o0;
                out_acc4[ob + 1] = o1;
                float sn = src_norm[node];
                uint4 hn;
                hn.x = f2bf(h0 * sn) | (f2bf(h1 * sn) << 16);
                hn.y = f2bf(h2 * sn) | (f2bf(h3 * sn) << 16);
                hn.z = f2bf(h4 * sn) | (f2bf(h5 * sn) << 16);
                hn.w = f2bf(h6 * sn) | (f2bf(h7 * sn) << 16);
                hs_next8[(size_t)node * 8 + lane] = hn;
            }
        }
    }
}

// ---------------- snap-mode final combine ----------------
__global__ void combine_kernel(const void* __restrict__ feat_raw,
                               const int* __restrict__ flags,
                               const int* __restrict__ out_deg,
                               const uint4* __restrict__ hs_base,
                               float4* __restrict__ out4,
                               Wts wts, int nchunks) {
    int i = blockIdx.x * blockDim.x + threadIdx.x;
    if (i >= nchunks) return;
    int n = i >> 3;
    float inv = sqrtf(fmaxf((float)out_deg[n], 1.0f));  // 1/src_norm
    float acc[8];
    if (flags[1]) {
        float4 a = ((const float4*)feat_raw)[i * 2];
        float4 b = ((const float4*)feat_raw)[i * 2 + 1];
        acc[0] = a.x; acc[1] = a.y; acc[2] = a.z; acc[3] = a.w;
        acc[4] = b.x; acc[5] = b.y; acc[6] = b.z; acc[7] = b.w;
    } else {
        uint4 u = ((const uint4*)feat_raw)[i];
        acc[0] = bits2f(u.x << 16); acc[1] = bits2f(u.x & 0xFFFF0000u);
        acc[2] = bits2f(u.y << 16); acc[3] = bits2f(u.y & 0xFFFF0000u);
        acc[4] = bits2f(u.z << 16); acc[5] = bits2f(u.z & 0xFFFF0000u);
        acc[6] = bits2f(u.w << 16); acc[7] = bits2f(u.w & 0xFFFF0000u);
    }
    float w0 = wts.v[0];
    #pragma unroll
    for (int j = 0; j < 8; ++j) acc[j] *= w0;
    #pragma unroll
    for (int k = 1; k <= K_STEPS; ++k) {
        uint4 u = hs_base[(size_t)k * nchunks + i];
        float s = wts.v[k] * inv;
        acc[0] += s * bits2f(u.x << 16); acc[1] += s * bits2f(u.x & 0xFFFF0000u);
        acc[2] += s * bits2f(u.y << 16); acc[3] += s * bits2f(u.y & 0xFFFF0000u);
        acc[4] += s * bits2f(u.z << 16); acc[5] += s * bits2f(u.z & 0xFFFF0000u);
        acc[6] += s * bits2f(u.w << 16); acc[7] += s * bits2f(u.w & 0xFFFF0000u);
    }
    float4 o0 = {acc[0], acc[1], acc[2], acc[3]};
    float4 o1 = {acc[4], acc[5], acc[6], acc[7]};
    out4[i * 2] = o0;
    out4[i * 2 + 1] = o1;
}

extern "C" void kernel_launch(void* const* d_in, const int* in_sizes, int n_in,
                              void* d_out, int out_size, void* d_ws, size_t ws_size,
                              hipStream_t stream) {
    const void* feat_raw = d_in[0];
    const void* src_raw = d_in[1];
    const void* dst_raw = d_in[2];
    float4* out4 = (float4*)d_out;

    const int N = in_sizes[0] / HIDDEN;
    const int E = (in_sizes[1] > 1500000) ? in_sizes[1] / 2 : in_sizes[1];
    const int nchunks = N * 8;
    const int nsb = (E + EPB - 1) / EPB;   // step blocks

    // ---- config ladder on ws_size (deterministic) ----
    auto align256 = [](size_t b) { return (b + 255) & ~(size_t)255; };
    size_t base_bytes = align256(2 * sizeof(int))
                      + align256((size_t)N * sizeof(int))
                      + align256((size_t)N * sizeof(int))
                      + align256((size_t)(N + 1) * sizeof(int))
                      + align256(1024 * sizeof(int))
                      + align256((size_t)E * sizeof(int))        // col
                      + align256((size_t)E * sizeof(int))        // dstid
                      + align256((size_t)(nsb + 1) * sizeof(int))// start
                      + align256((size_t)N * sizeof(float))
                      + align256((size_t)N * sizeof(float));
    auto hist_bytes = [&](int C) {
        return align256((size_t)2 * SLICES * C * SLICE_W * sizeof(unsigned))
             + align256((size_t)C * SLICES * SLICE_W * sizeof(unsigned));
    };
    size_t snap_bytes = align256((size_t)(K_STEPS + 1) * nchunks * sizeof(uint4));
    size_t acc_bytes  = align256((size_t)2 * nchunks * sizeof(uint4))
                      + align256((size_t)N * 16 * sizeof(float4));

    int CH;
    int snapMode;
    if      (ws_size >= base_bytes + hist_bytes(128) + snap_bytes) { CH = 128; snapMode = 1; }
    else if (ws_size >= base_bytes + hist_bytes(64)  + snap_bytes) { CH = 64;  snapMode = 1; }
    else if (ws_size >= base_bytes + hist_bytes(128) + acc_bytes)  { CH = 128; snapMode = 0; }
    else                                                           { CH = 64;  snapMode = 0; }
    const int chunkE = (E + CH - 1) / CH;

    // ---- workspace carve-up ----
    char* p = (char*)d_ws;
    auto alloc = [&](size_t bytes) {
        char* r = p;
        p += (bytes + 255) & ~(size_t)255;
        return r;
    };
    int* flags = (int*)alloc(2 * sizeof(int));
    int* out_deg = (int*)alloc((size_t)N * sizeof(int));
    int* in_deg = (int*)alloc((size_t)N * sizeof(int));
    int* row_ptr = (int*)alloc((size_t)(N + 1) * sizeof(int));
    int* block_sums = (int*)alloc(1024 * sizeof(int));
    int* col = (int*)alloc((size_t)E * sizeof(int));
    int* dstid = (int*)alloc((size_t)E * sizeof(int));
    int* start = (int*)alloc((size_t)(nsb + 1) * sizeof(int));
    float* src_norm = (float*)alloc((size_t)N * sizeof(float));
    float* dst_norm = (float*)alloc((size_t)N * sizeof(float));
    unsigned* partials = (unsigned*)alloc((size_t)2 * SLICES * CH * SLICE_W * sizeof(unsigned));
    unsigned* chunk_pre = (unsigned*)alloc((size_t)CH * SLICES * SLICE_W * sizeof(unsigned));
    uint4* hs_region;
    float4* out_acc = nullptr;
    if (snapMode) {
        hs_region = (uint4*)alloc((size_t)(K_STEPS + 1) * nchunks * sizeof(uint4));
    } else {
        hs_region = (uint4*)alloc((size_t)2 * nchunks * sizeof(uint4));
        out_acc = (float4*)alloc((size_t)N * 16 * sizeof(float4));
    }

    // ---- combination weights ----
    double logs[K_STEPS + 1];
    double denom = 0.0;
    for (int i = 0; i < K_STEPS + 1; ++i) {
        logs[i] = log(2.0 + (double)(i + 1));
        denom += logs[i];
    }
    Wts wts;
    for (int i = 0; i < K_STEPS + 1; ++i) wts.v[i] = (float)(logs[i] / denom);

    // ---- pipeline ----
    detect_kernel<<<1, 256, 0, stream>>>((const int*)src_raw,
                                         (const unsigned short*)feat_raw, flags);
    hist_kernel<<<dim3(CH, SLICES, 2), 256, 0, stream>>>(src_raw, dst_raw, flags,
                                                         partials, E, chunkE, CH);
    reduce_kernel<<<(2 * SLICES * SLICE_W + 255) / 256, 256, 0, stream>>>(
        partials, chunk_pre, out_deg, in_deg, N, CH);
    norm_kernel<<<(N + 255) / 256, 256, 0, stream>>>(out_deg, in_deg, src_norm, dst_norm, N);

    int nb = (N + 1023) / 1024;
    scanA_kernel<<<nb, 256, 0, stream>>>(in_deg, row_ptr, block_sums, N);
    scanB_kernel<<<1, 1024, 0, stream>>>(block_sums, nb);
    scanC_kernel<<<(N + 255) / 256, 256, 0, stream>>>(block_sums, row_ptr, N, E);
    fill_kernel<<<dim3(CH, SLICES), 256, 0, stream>>>(src_raw, dst_raw, flags,
                                                      row_ptr, chunk_pre, col, dstid,
                                                      E, chunkE);
    partition_kernel<<<(nsb + 256) / 256, 256, 0, stream>>>(row_ptr, start, nsb, N);

    init_kernel<<<(nchunks + 255) / 256, 256, 0, stream>>>(
        feat_raw, flags, src_norm, hs_region, out_acc, wts.v[0], nchunks, snapMode ? 0 : 1);

    if (snapMode) {
        for (int step = 0; step < K_STEPS; ++step) {
            const uint4* cur = hs_region + (size_t)step * nchunks;
            uint4* nxt = hs_region + (size_t)(step + 1) * nchunks;
            step_edge<<<nsb, 256, 0, stream>>>(cur, row_ptr, col, dstid, start,
                                               src_norm, dst_norm, nxt, N);
        }
        combine_kernel<<<(nchunks + 255) / 256, 256, 0, stream>>>(
            feat_raw, flags, out_deg, hs_region, out4, wts, nchunks);
    } else {
        uint4* cur = hs_region;
        uint4* nxt = hs_region + nchunks;
        for (int step = 0; step < K_STEPS; ++step) {
            if (step == K_STEPS - 1) {
                step_acc<true><<<2048, 256, 0, stream>>>(
                    cur, row_ptr, col, src_norm, dst_norm, nxt, out_acc, out4,
                    wts.v[step + 1], N);
            } else {
                step_acc<false><<<2048, 256, 0, stream>>>(
                    cur, row_ptr, col, src_norm, dst_norm, nxt, out_acc, out4,
                    wts.v[step + 1], N);
            }
            uint4* t = cur; cur = nxt; nxt = t;
        }
    }
}

// Round 11
// 567.111 us; speedup vs baseline: 6.3553x; 6.3553x over previous
//
#include <hip/hip_runtime.h>
#include <hip/hip_bf16.h>
#include <math.h>

#define HIDDEN 64
#define K_STEPS 10
#define SLICES 2
#define SLICE_N 51200              // 2*51200 = 102400 >= N
#define SLICE_W (SLICE_N / 4)      // packed-byte words per slice (12800 = 51.2KB LDS)

struct Wts { float v[K_STEPS + 1]; };

typedef float v2f __attribute__((ext_vector_type(2)));

__device__ __forceinline__ float bits2f(unsigned int u) {
    union { unsigned int i; float f; } c; c.i = u; return c.f;
}
__device__ __forceinline__ unsigned short f2bf(float f) {
    union { float f; unsigned int u; } c; c.f = f;
    unsigned int u = c.u;
    return (unsigned short)((u + 0x7FFF + ((u >> 16) & 1)) >> 16);  // RNE
}
// unpack one uint4 (8 bf16) and accumulate into 4 packed-float2 accumulators
__device__ __forceinline__ void unpack_add(v2f acc[4], uint4 v) {
    v2f t;
    t.x = bits2f(v.x << 16); t.y = bits2f(v.x & 0xFFFF0000u); acc[0] += t;
    t.x = bits2f(v.y << 16); t.y = bits2f(v.y & 0xFFFF0000u); acc[1] += t;
    t.x = bits2f(v.z << 16); t.y = bits2f(v.z & 0xFFFF0000u); acc[2] += t;
    t.x = bits2f(v.w << 16); t.y = bits2f(v.w & 0xFFFF0000u); acc[3] += t;
}

// ---------------- dtype sniffing ----------------
__global__ void detect_kernel(const int* __restrict__ srcw,
                              const unsigned short* __restrict__ featw,
                              int* __restrict__ flags) {
    __shared__ int odd_nonzero;
    __shared__ int exp_in_range;
    if (threadIdx.x == 0) { odd_nonzero = 0; exp_in_range = 0; }
    __syncthreads();
    int w = srcw[2 * threadIdx.x + 1];
    if (w != 0) atomicAdd(&odd_nonzero, 1);
    unsigned short f = featw[2 * threadIdx.x];
    int ex = (f >> 7) & 0xFF;
    if (ex >= 90 && ex <= 135) atomicAdd(&exp_in_range, 1);
    __syncthreads();
    if (threadIdx.x == 0) {
        flags[0] = (odd_nonzero == 0) ? 1 : 0;    // int64 indices
        flags[1] = (exp_in_range >= 240) ? 0 : 1; // fp32 feat
    }
}

// ---------------- LDS byte-packed degree histogram ----------------
__global__ void hist_kernel(const void* __restrict__ src, const void* __restrict__ dst,
                            const int* __restrict__ flags,
                            unsigned* __restrict__ partials, int E, int chunkE, int nchunks) {
    __shared__ unsigned bins[SLICE_W];
    int cx = blockIdx.x, sy = blockIdx.y, az = blockIdx.z;
    for (int i = threadIdx.x; i < SLICE_W; i += 256) bins[i] = 0;
    __syncthreads();
    const void* arr = az ? dst : src;
    int i64 = flags[0];
    int base = cx * chunkE;
    int lim = min(base + chunkE, E);
    int sliceBase = sy * SLICE_N;
    for (int e = base + threadIdx.x; e < lim; e += 256) {
        int v = i64 ? (int)((const long long*)arr)[e] : ((const int*)arr)[e];
        unsigned local = (unsigned)(v - sliceBase);
        if (local < SLICE_N)
            atomicAdd(&bins[local >> 2], 1u << ((local & 3) * 8));
    }
    __syncthreads();
    unsigned* out = partials + ((size_t)((az * SLICES + sy) * nchunks + cx)) * SLICE_W;
    for (int i = threadIdx.x; i < SLICE_W; i += 256) out[i] = bins[i];
}

// ---------------- merge partials -> degrees; per-chunk prefixes for dst ----------------
__global__ void reduce_kernel(const unsigned* __restrict__ partials,
                              unsigned* __restrict__ chunk_pre,
                              int* __restrict__ out_deg, int* __restrict__ in_deg,
                              int N, int nchunks) {
    int t = blockIdx.x * blockDim.x + threadIdx.x;
    if (t >= 2 * SLICES * SLICE_W) return;
    int a = t / (SLICES * SLICE_W);
    int r = t % (SLICES * SLICE_W);
    int s = r / SLICE_W;
    int lw = r % SLICE_W;
    const unsigned* p = partials + ((size_t)((a * SLICES + s) * nchunks)) * SLICE_W + lw;
    unsigned sum = 0;
    if (a == 1) {
        for (int c = 0; c < nchunks; ++c) {
            chunk_pre[((size_t)(c * SLICES + s)) * SLICE_W + lw] = sum;
            sum += p[(size_t)c * SLICE_W];
        }
    } else {
        for (int c = 0; c < nchunks; ++c) sum += p[(size_t)c * SLICE_W];
    }
    int nodeBase = s * SLICE_N + lw * 4;
    int* deg = a ? in_deg : out_deg;
    #pragma unroll
    for (int k = 0; k < 4; ++k) {
        int n = nodeBase + k;
        if (n < N) deg[n] = (int)((sum >> (k * 8)) & 0xFF);
    }
}

// ---------------- norms ----------------
__global__ void norm_kernel(const int* __restrict__ out_deg, const int* __restrict__ in_deg,
                            float* __restrict__ src_norm, float* __restrict__ dst_norm, int N) {
    int n = blockIdx.x * blockDim.x + threadIdx.x;
    if (n < N) {
        src_norm[n] = 1.0f / sqrtf(fmaxf((float)out_deg[n], 1.0f));
        dst_norm[n] = 1.0f / sqrtf(fmaxf((float)in_deg[n], 1.0f));
    }
}

// ---------------- scan A ----------------
__global__ void scanA_kernel(const int* __restrict__ deg, int* __restrict__ row_ptr,
                             int* __restrict__ block_sums, int N) {
    __shared__ int lds[256];
    int t = threadIdx.x;
    int base = blockIdx.x * 1024 + t * 4;
    int v0 = (base + 0 < N) ? deg[base + 0] : 0;
    int v1 = (base + 1 < N) ? deg[base + 1] : 0;
    int v2 = (base + 2 < N) ? deg[base + 2] : 0;
    int v3 = (base + 3 < N) ? deg[base + 3] : 0;
    int s = v0 + v1 + v2 + v3;
    lds[t] = s;
    __syncthreads();
    for (int off = 1; off < 256; off <<= 1) {
        int x = 0;
        if (t >= off) x = lds[t - off];
        __syncthreads();
        if (t >= off) lds[t] += x;
        __syncthreads();
    }
    int excl = lds[t] - s;
    if (t == 255) block_sums[blockIdx.x] = lds[255];
    if (base + 0 < N) row_ptr[base + 0] = excl;
    if (base + 1 < N) row_ptr[base + 1] = excl + v0;
    if (base + 2 < N) row_ptr[base + 2] = excl + v0 + v1;
    if (base + 3 < N) row_ptr[base + 3] = excl + v0 + v1 + v2;
}

// ---------------- scan B ----------------
__global__ void scanB_kernel(int* __restrict__ bs, int nb) {
    __shared__ int lds[1024];
    int t = threadIdx.x;
    int v = (t < nb) ? bs[t] : 0;
    lds[t] = v;
    __syncthreads();
    for (int off = 1; off < 1024; off <<= 1) {
        int x = 0;
        if (t >= off) x = lds[t - off];
        __syncthreads();
        if (t >= off) lds[t] += x;
        __syncthreads();
    }
    if (t < nb) bs[t] = lds[t] - v;
}

// ---------------- scan C ----------------
__global__ void scanC_kernel(const int* __restrict__ block_offs, int* __restrict__ row_ptr,
                             int N, int E) {
    int i = blockIdx.x * blockDim.x + threadIdx.x;
    if (i < N) row_ptr[i] += block_offs[i >> 10];
    if (i == 0) row_ptr[N] = E;
}

// ---------------- CSR fill ----------------
__global__ void fill_kernel(const void* __restrict__ src, const void* __restrict__ dst,
                            const int* __restrict__ flags,
                            const int* __restrict__ row_ptr,
                            const unsigned* __restrict__ chunk_pre,
                            int* __restrict__ col, int E, int chunkE) {
    __shared__ unsigned bins[SLICE_W];
    int cx = blockIdx.x, sy = blockIdx.y;
    for (int i = threadIdx.x; i < SLICE_W; i += 256) bins[i] = 0;
    __syncthreads();
    int i64 = flags[0];
    int base = cx * chunkE;
    int lim = min(base + chunkE, E);
    int sliceBase = sy * SLICE_N;
    const unsigned* pre_base = chunk_pre + ((size_t)(cx * SLICES + sy)) * SLICE_W;
    for (int e = base + threadIdx.x; e < lim; e += 256) {
        int s, d;
        if (i64) { s = (int)((const long long*)src)[e]; d = (int)((const long long*)dst)[e]; }
        else     { s = ((const int*)src)[e];            d = ((const int*)dst)[e]; }
        unsigned local = (unsigned)(d - sliceBase);
        if (local < SLICE_N) {
            int sh = (local & 3) * 8;
            unsigned old = atomicAdd(&bins[local >> 2], 1u << sh);
            int rank = (int)((old >> sh) & 0xFF);
            int pre = (int)((pre_base[local >> 2] >> sh) & 0xFF);
            col[row_ptr[d] + pre + rank] = s;
        }
    }
}

// ---------------- init ----------------
__global__ void init_kernel(const void* __restrict__ feat_raw,
                            const int* __restrict__ flags,
                            const float* __restrict__ src_norm,
                            uint4* __restrict__ hs8, float4* __restrict__ out_acc4,
                            float w0, int nchunks, int writeAcc) {
    int i = blockIdx.x * blockDim.x + threadIdx.x;
    if (i >= nchunks) return;
    int n = i >> 3;
    int c = i & 7;
    float sn = src_norm[n];
    float f[8];
    if (flags[1]) {
        float4 a = ((const float4*)feat_raw)[i * 2];
        float4 b = ((const float4*)feat_raw)[i * 2 + 1];
        f[0] = a.x; f[1] = a.y; f[2] = a.z; f[3] = a.w;
        f[4] = b.x; f[5] = b.y; f[6] = b.z; f[7] = b.w;
    } else {
        uint4 u = ((const uint4*)feat_raw)[i];
        f[0] = bits2f(u.x << 16); f[1] = bits2f(u.x & 0xFFFF0000u);
        f[2] = bits2f(u.y << 16); f[3] = bits2f(u.y & 0xFFFF0000u);
        f[4] = bits2f(u.z << 16); f[5] = bits2f(u.z & 0xFFFF0000u);
        f[6] = bits2f(u.w << 16); f[7] = bits2f(u.w & 0xFFFF0000u);
    }
    uint4 h;
    h.x = (unsigned int)f2bf(f[0] * sn) | ((unsigned int)f2bf(f[1] * sn) << 16);
    h.y = (unsigned int)f2bf(f[2] * sn) | ((unsigned int)f2bf(f[3] * sn) << 16);
    h.z = (unsigned int)f2bf(f[4] * sn) | ((unsigned int)f2bf(f[5] * sn) << 16);
    h.w = (unsigned int)f2bf(f[6] * sn) | ((unsigned int)f2bf(f[7] * sn) << 16);
    hs8[i] = h;
    if (writeAcc) {
        float4 o0, o1;
        o0.x = w0 * f[0]; o0.y = w0 * f[1]; o0.z = w0 * f[2]; o0.w = w0 * f[3];
        o1.x = w0 * f[4]; o1.y = w0 * f[5]; o1.z = w0 * f[6]; o1.w = w0 * f[7];
        size_t ob = (size_t)n * 16 + c * 2;
        out_acc4[ob] = o0;
        out_acc4[ob + 1] = o1;
    }
}

// ---------------- single-node gather ----------------
__device__ __forceinline__ void gather_range(const uint4* __restrict__ hs8,
                                             const int* __restrict__ col,
                                             int beg, int end, int lane,
                                             v2f a0[4]) {
    int grp = lane >> 3;
    int fo = lane & 7;
    v2f a1[4] = {v2f{0.f,0.f}, v2f{0.f,0.f}, v2f{0.f,0.f}, v2f{0.f,0.f}};
    for (int ebase = beg; ebase < end; ebase += 64) {
        int myE = ebase + lane;
        int myCol = (myE < end) ? col[myE] : 0;
        int cnt = min(64, end - ebase);
        int j = 0;
        for (; j + 16 <= cnt; j += 16) {
            int s0 = __shfl(myCol, j + grp);
            int s1 = __shfl(myCol, j + 8 + grp);
            uint4 v0 = hs8[(size_t)s0 * 8 + fo];
            uint4 v1 = hs8[(size_t)s1 * 8 + fo];
            unpack_add(a0, v0);
            unpack_add(a1, v1);
        }
        if (j + 8 <= cnt) {
            int s0 = __shfl(myCol, j + grp);
            uint4 v0 = hs8[(size_t)s0 * 8 + fo];
            unpack_add(a0, v0);
            j += 8;
        }
        {
            int g = j + grp;
            int s = __shfl(myCol, (g < cnt) ? g : 0);
            if (g < cnt) {
                uint4 v1 = hs8[(size_t)s * 8 + fo];
                unpack_add(a1, v1);
            }
        }
    }
    #pragma unroll
    for (int k = 0; k < 4; ++k) a0[k] += a1[k];
    #pragma unroll
    for (int off = 8; off <= 32; off <<= 1) {
        #pragma unroll
        for (int k = 0; k < 4; ++k) {
            v2f t;
            t.x = __shfl_xor(a0[k].x, off);
            t.y = __shfl_xor(a0[k].y, off);
            a0[k] += t;
        }
    }
}

// ---------------- snap-mode step: persistent waves, grid-stride over nodes ----------------
__global__ __launch_bounds__(256) void step_snap(
        const uint4* __restrict__ hs8, const int* __restrict__ row_ptr,
        const int* __restrict__ col, const float* __restrict__ src_norm,
        const float* __restrict__ dst_norm, uint4* __restrict__ hs_next8, int N) {
    int wid = (blockIdx.x * 256 + threadIdx.x) >> 6;
    int nw = (gridDim.x * 256) >> 6;
    int lane = threadIdx.x & 63;
    for (int node = wid; node < N; node += nw) {
        v2f a[4] = {v2f{0.f,0.f}, v2f{0.f,0.f}, v2f{0.f,0.f}, v2f{0.f,0.f}};
        gather_range(hs8, col, row_ptr[node], row_ptr[node + 1], lane, a);
        if (lane < 8) {
            float m = dst_norm[node] * src_norm[node];
            uint4 hn;
            hn.x = (unsigned int)f2bf(a[0].x * m) | ((unsigned int)f2bf(a[0].y * m) << 16);
            hn.y = (unsigned int)f2bf(a[1].x * m) | ((unsigned int)f2bf(a[1].y * m) << 16);
            hn.z = (unsigned int)f2bf(a[2].x * m) | ((unsigned int)f2bf(a[2].y * m) << 16);
            hn.w = (unsigned int)f2bf(a[3].x * m) | ((unsigned int)f2bf(a[3].y * m) << 16);
            hs_next8[(size_t)node * 8 + lane] = hn;
        }
    }
}

// ---------------- acc-mode step (fallback) ----------------
template <bool LAST>
__global__ __launch_bounds__(256) void step_acc(
        const uint4* __restrict__ hs8, const int* __restrict__ row_ptr,
        const int* __restrict__ col, const float* __restrict__ src_norm,
        const float* __restrict__ dst_norm, uint4* __restrict__ hs_next8,
        float4* __restrict__ out_acc4, float4* __restrict__ out4, float w, int N) {
    int wid = (blockIdx.x * 256 + threadIdx.x) >> 6;
    int nw = (gridDim.x * 256) >> 6;
    int lane = threadIdx.x & 63;
    for (int node = wid; node < N; node += nw) {
        v2f a[4] = {v2f{0.f,0.f}, v2f{0.f,0.f}, v2f{0.f,0.f}, v2f{0.f,0.f}};
        gather_range(hs8, col, row_ptr[node], row_ptr[node + 1], lane, a);
        if (lane < 8) {
            float dn = dst_norm[node];
            float h0 = a[0].x * dn, h1 = a[0].y * dn, h2 = a[1].x * dn, h3 = a[1].y * dn;
            float h4 = a[2].x * dn, h5 = a[2].y * dn, h6 = a[3].x * dn, h7 = a[3].y * dn;
            size_t ob = (size_t)node * 16 + lane * 2;
            float4 o0 = out_acc4[ob];
            float4 o1 = out_acc4[ob + 1];
            o0.x += w * h0; o0.y += w * h1; o0.z += w * h2; o0.w += w * h3;
            o1.x += w * h4; o1.y += w * h5; o1.z += w * h6; o1.w += w * h7;
            if (LAST) {
                out4[ob] = o0;
                out4[ob + 1] = o1;
            } else {
                out_acc4[ob] = o0;
                out_acc4[ob + 1] = o1;
                float sn = src_norm[node];
                uint4 hn;
                hn.x = (unsigned int)f2bf(h0 * sn) | ((unsigned int)f2bf(h1 * sn) << 16);
                hn.y = (unsigned int)f2bf(h2 * sn) | ((unsigned int)f2bf(h3 * sn) << 16);
                hn.z = (unsigned int)f2bf(h4 * sn) | ((unsigned int)f2bf(h5 * sn) << 16);
                hn.w = (unsigned int)f2bf(h6 * sn) | ((unsigned int)f2bf(h7 * sn) << 16);
                hs_next8[(size_t)node * 8 + lane] = hn;
            }
        }
    }
}

// ---------------- snap-mode final combine ----------------
__global__ void combine_kernel(const void* __restrict__ feat_raw,
                               const int* __restrict__ flags,
                               const int* __restrict__ out_deg,
                               const uint4* __restrict__ hs_base,
                               float4* __restrict__ out4,
                               Wts wts, int nchunks) {
    int i = blockIdx.x * blockDim.x + threadIdx.x;
    if (i >= nchunks) return;
    int n = i >> 3;
    float inv = sqrtf(fmaxf((float)out_deg[n], 1.0f));  // 1/src_norm
    float acc[8];
    if (flags[1]) {
        float4 a = ((const float4*)feat_raw)[i * 2];
        float4 b = ((const float4*)feat_raw)[i * 2 + 1];
        acc[0] = a.x; acc[1] = a.y; acc[2] = a.z; acc[3] = a.w;
        acc[4] = b.x; acc[5] = b.y; acc[6] = b.z; acc[7] = b.w;
    } else {
        uint4 u = ((const uint4*)feat_raw)[i];
        acc[0] = bits2f(u.x << 16); acc[1] = bits2f(u.x & 0xFFFF0000u);
        acc[2] = bits2f(u.y << 16); acc[3] = bits2f(u.y & 0xFFFF0000u);
        acc[4] = bits2f(u.z << 16); acc[5] = bits2f(u.z & 0xFFFF0000u);
        acc[6] = bits2f(u.w << 16); acc[7] = bits2f(u.w & 0xFFFF0000u);
    }
    float w0 = wts.v[0];
    #pragma unroll
    for (int j = 0; j < 8; ++j) acc[j] *= w0;
    #pragma unroll
    for (int k = 1; k <= K_STEPS; ++k) {
        uint4 u = hs_base[(size_t)k * nchunks + i];
        float s = wts.v[k] * inv;
        acc[0] += s * bits2f(u.x << 16); acc[1] += s * bits2f(u.x & 0xFFFF0000u);
        acc[2] += s * bits2f(u.y << 16); acc[3] += s * bits2f(u.y & 0xFFFF0000u);
        acc[4] += s * bits2f(u.z << 16); acc[5] += s * bits2f(u.z & 0xFFFF0000u);
        acc[6] += s * bits2f(u.w << 16); acc[7] += s * bits2f(u.w & 0xFFFF0000u);
    }
    float4 o0 = {acc[0], acc[1], acc[2], acc[3]};
    float4 o1 = {acc[4], acc[5], acc[6], acc[7]};
    out4[i * 2] = o0;
    out4[i * 2 + 1] = o1;
}

extern "C" void kernel_launch(void* const* d_in, const int* in_sizes, int n_in,
                              void* d_out, int out_size, void* d_ws, size_t ws_size,
                              hipStream_t stream) {
    const void* feat_raw = d_in[0];
    const void* src_raw = d_in[1];
    const void* dst_raw = d_in[2];
    float4* out4 = (float4*)d_out;

    const int N = in_sizes[0] / HIDDEN;
    const int E = (in_sizes[1] > 1500000) ? in_sizes[1] / 2 : in_sizes[1];
    const int nchunks = N * 8;

    // ---- config ladder on ws_size (deterministic) ----
    auto align256 = [](size_t b) { return (b + 255) & ~(size_t)255; };
    size_t base_bytes = align256(2 * sizeof(int))
                      + align256((size_t)N * sizeof(int))
                      + align256((size_t)N * sizeof(int))
                      + align256((size_t)(N + 1) * sizeof(int))
                      + align256(1024 * sizeof(int))
                      + align256((size_t)E * sizeof(int))
                      + align256((size_t)N * sizeof(float))
                      + align256((size_t)N * sizeof(float));
    auto hist_bytes = [&](int C) {
        return align256((size_t)2 * SLICES * C * SLICE_W * sizeof(unsigned))
             + align256((size_t)C * SLICES * SLICE_W * sizeof(unsigned));
    };
    size_t snap_bytes = align256((size_t)(K_STEPS + 1) * nchunks * sizeof(uint4));
    size_t acc_bytes  = align256((size_t)2 * nchunks * sizeof(uint4))
                      + align256((size_t)N * 16 * sizeof(float4));

    int CH;
    int snapMode;
    if      (ws_size >= base_bytes + hist_bytes(128) + snap_bytes) { CH = 128; snapMode = 1; }
    else if (ws_size >= base_bytes + hist_bytes(64)  + snap_bytes) { CH = 64;  snapMode = 1; }
    else if (ws_size >= base_bytes + hist_bytes(128) + acc_bytes)  { CH = 128; snapMode = 0; }
    else                                                           { CH = 64;  snapMode = 0; }
    const int chunkE = (E + CH - 1) / CH;

    // ---- workspace carve-up ----
    char* p = (char*)d_ws;
    auto alloc = [&](size_t bytes) {
        char* r = p;
        p += (bytes + 255) & ~(size_t)255;
        return r;
    };
    int* flags = (int*)alloc(2 * sizeof(int));
    int* out_deg = (int*)alloc((size_t)N * sizeof(int));
    int* in_deg = (int*)alloc((size_t)N * sizeof(int));
    int* row_ptr = (int*)alloc((size_t)(N + 1) * sizeof(int));
    int* block_sums = (int*)alloc(1024 * sizeof(int));
    int* col = (int*)alloc((size_t)E * sizeof(int));
    float* src_norm = (float*)alloc((size_t)N * sizeof(float));
    float* dst_norm = (float*)alloc((size_t)N * sizeof(float));
    unsigned* partials = (unsigned*)alloc((size_t)2 * SLICES * CH * SLICE_W * sizeof(unsigned));
    unsigned* chunk_pre = (unsigned*)alloc((size_t)CH * SLICES * SLICE_W * sizeof(unsigned));
    uint4* hs_region;
    float4* out_acc = nullptr;
    if (snapMode) {
        hs_region = (uint4*)alloc((size_t)(K_STEPS + 1) * nchunks * sizeof(uint4));
    } else {
        hs_region = (uint4*)alloc((size_t)2 * nchunks * sizeof(uint4));
        out_acc = (float4*)alloc((size_t)N * 16 * sizeof(float4));
    }

    // ---- combination weights ----
    double logs[K_STEPS + 1];
    double denom = 0.0;
    for (int i = 0; i < K_STEPS + 1; ++i) {
        logs[i] = log(2.0 + (double)(i + 1));
        denom += logs[i];
    }
    Wts wts;
    for (int i = 0; i < K_STEPS + 1; ++i) wts.v[i] = (float)(logs[i] / denom);

    // ---- pipeline ----
    detect_kernel<<<1, 256, 0, stream>>>((const int*)src_raw,
                                         (const unsigned short*)feat_raw, flags);
    hist_kernel<<<dim3(CH, SLICES, 2), 256, 0, stream>>>(src_raw, dst_raw, flags,
                                                         partials, E, chunkE, CH);
    reduce_kernel<<<(2 * SLICES * SLICE_W + 255) / 256, 256, 0, stream>>>(
        partials, chunk_pre, out_deg, in_deg, N, CH);
    norm_kernel<<<(N + 255) / 256, 256, 0, stream>>>(out_deg, in_deg, src_norm, dst_norm, N);

    int nb = (N + 1023) / 1024;
    scanA_kernel<<<nb, 256, 0, stream>>>(in_deg, row_ptr, block_sums, N);
    scanB_kernel<<<1, 1024, 0, stream>>>(block_sums, nb);
    scanC_kernel<<<(N + 255) / 256, 256, 0, stream>>>(block_sums, row_ptr, N, E);
    fill_kernel<<<dim3(CH, SLICES), 256, 0, stream>>>(src_raw, dst_raw, flags,
                                                      row_ptr, chunk_pre, col, E, chunkE);

    init_kernel<<<(nchunks + 255) / 256, 256, 0, stream>>>(
        feat_raw, flags, src_norm, hs_region, out_acc, wts.v[0], nchunks, snapMode ? 0 : 1);

    const int step_blocks = 2048;  // persistent: 8192 waves = full residency
    if (snapMode) {
        for (int step = 0; step < K_STEPS; ++step) {
            const uint4* cur = hs_region + (size_t)step * nchunks;
            uint4* nxt = hs_region + (size_t)(step + 1) * nchunks;
            step_snap<<<step_blocks, 256, 0, stream>>>(cur, row_ptr, col, src_norm,
                                                       dst_norm, nxt, N);
        }
        combine_kernel<<<(nchunks + 255) / 256, 256, 0, stream>>>(
            feat_raw, flags, out_deg, hs_region, out4, wts, nchunks);
    } else {
        uint4* cur = hs_region;
        uint4* nxt = hs_region + nchunks;
        for (int step = 0; step < K_STEPS; ++step) {
            if (step == K_STEPS - 1) {
                step_acc<true><<<step_blocks, 256, 0, stream>>>(
                    cur, row_ptr, col, src_norm, dst_norm, nxt, out_acc, out4,
                    wts.v[step + 1], N);
            } else {
                step_acc<false><<<step_blocks, 256, 0, stream>>>(
                    cur, row_ptr, col, src_norm, dst_norm, nxt, out_acc, out4,
                    wts.v[step + 1], N);
            }
            uint4* t = cur; cur = nxt; nxt = t;
        }
    }
}